// Round 1
// baseline (458.662 us; speedup 1.0000x reference)
//
#include <hip/hip_runtime.h>
#include <stdint.h>

#define NB 16384       // batch rows
#define DI 2048        // d_in
#define DO 2048        // d_out
#define KTOP 256
#define LIST_CAP 384
#define MT (NB / 128)  // 128 row tiles for partial sums

typedef __attribute__((ext_vector_type(4))) float f32x4;
typedef __attribute__((ext_vector_type(8))) short s16x8;
typedef __attribute__((ext_vector_type(8))) unsigned short u16x8;

// OWA weights: w(rank) = (1 - 0.9*rank/255)/140.8
#define OWA_C0 7.10227273e-3f
#define OWA_C1 2.50668449e-5f

__device__ __forceinline__ ushort f2bf(float f) {
  uint32_t u = __float_as_uint(f);
  uint32_t r = (u + 0x7FFFu + ((u >> 16) & 1u)) >> 16;  // RNE
  return (ushort)r;
}

__device__ __forceinline__ void gld_lds16(const void* g, void* l) {
  __builtin_amdgcn_global_load_lds((__attribute__((address_space(1))) void*)g,
                                   (__attribute__((address_space(3))) void*)l,
                                   16, 0, 0);
}

// ---------------------------------------------------------------------------
// K0: convert W (fp32 [DO][DI]) -> bf16
__global__ __launch_bounds__(256) void k_cvt(const float* __restrict__ W,
                                             ushort* __restrict__ Wb) {
  size_t i = ((size_t)blockIdx.x * 256 + threadIdx.x) * 8;
  float4 a = *(const float4*)(W + i);
  float4 b = *(const float4*)(W + i + 4);
  u16x8 o;
  o[0] = f2bf(a.x); o[1] = f2bf(a.y); o[2] = f2bf(a.z); o[3] = f2bf(a.w);
  o[4] = f2bf(b.x); o[5] = f2bf(b.y); o[6] = f2bf(b.z); o[7] = f2bf(b.w);
  *(u16x8*)(Wb + i) = o;
}

// ---------------------------------------------------------------------------
// K1: per-row mu + top-k(256) OWA -> A (bf16). One block (256 thr) per row.
__global__ __launch_bounds__(256) void k_topk(
    const float* __restrict__ x, const float* __restrict__ center,
    const float* __restrict__ sharp, float* __restrict__ mu_out,
    ushort* __restrict__ A) {
  __shared__ __align__(16) float w_lds[DI];   // OWA weight per column (0 if not selected)
  __shared__ uint32_t histR[8 * 256];         // 8-way replicated histogram
  __shared__ uint64_t list[LIST_CAP];         // candidate keys (bits<<32 | (DI-1-idx))
  __shared__ uint32_t scal[4];

  const int t = threadIdx.x;
  const int lane = t & 63;
  const int wv = t >> 6;
  const int row = blockIdx.x;
  const int base = t * 8;

  const float* xr = x + (size_t)row * DI + base;
  float4 xa = *(const float4*)(xr);
  float4 xb = *(const float4*)(xr + 4);
  float4 ca = *(const float4*)(center + base);
  float4 cb = *(const float4*)(center + base + 4);
  float4 sa = *(const float4*)(sharp + base);
  float4 sb = *(const float4*)(sharp + base + 4);

  float xv[8] = {xa.x, xa.y, xa.z, xa.w, xb.x, xb.y, xb.z, xb.w};
  float cv[8] = {ca.x, ca.y, ca.z, ca.w, cb.x, cb.y, cb.z, cb.w};
  float sv[8] = {sa.x, sa.y, sa.z, sa.w, sb.x, sb.y, sb.z, sb.w};
  float muv[8];
  uint32_t bits[8];
#pragma unroll
  for (int e = 0; e < 8; ++e) {
    float s = sv[e] * (xv[e] - cv[e]);
    float m = 1.0f / (1.0f + expf(-s));
    muv[e] = m;
    bits[e] = __float_as_uint(m);  // mu>0 -> bit pattern is order-preserving
  }
  if (mu_out) {
    float4 m0; m0.x = muv[0]; m0.y = muv[1]; m0.z = muv[2]; m0.w = muv[3];
    float4 m1; m1.x = muv[4]; m1.y = muv[5]; m1.z = muv[6]; m1.w = muv[7];
    *(float4*)(mu_out + (size_t)row * DI + base) = m0;
    *(float4*)(mu_out + (size_t)row * DI + base + 4) = m1;
  }
  // zero weight array (scattered into much later; barriers in between)
  float4 z4; z4.x = z4.y = z4.z = z4.w = 0.f;
  *(float4*)(w_lds + base) = z4;
  *(float4*)(w_lds + base + 4) = z4;

  // ---- 4-pass byte radix select for the 256th-largest bit pattern ----
  uint32_t maskHi = 0, pfx = 0;
  uint32_t k_rem = KTOP;
  const uint32_t rep = (uint32_t)(t & 7) * 256u;
#pragma unroll 1
  for (int pass = 0; pass < 4; ++pass) {
    const int shift = 24 - pass * 8;
#pragma unroll
    for (int i = 0; i < 8; ++i) histR[t + 256 * i] = 0;
    __syncthreads();
#pragma unroll
    for (int e = 0; e < 8; ++e) {
      uint32_t bb = bits[e];
      if ((bb & maskHi) == pfx)
        atomicAdd(&histR[rep + ((bb >> shift) & 255u)], 1u);
    }
    __syncthreads();
    if (wv == 0) {  // single-wave suffix scan over 256 bins, no barriers
      uint32_t c0 = 0, c1 = 0, c2 = 0, c3 = 0;
#pragma unroll
      for (int r = 0; r < 8; ++r) {
        const uint32_t* h = &histR[r * 256 + lane * 4];
        c0 += h[0]; c1 += h[1]; c2 += h[2]; c3 += h[3];
      }
      uint32_t s3 = c3, s2 = c2 + s3, s1 = c1 + s2, s0 = c0 + s1;
      uint32_t Tl = s0, suf = s0;
#pragma unroll
      for (int off = 1; off < 64; off <<= 1) {
        uint32_t vsh = __shfl_down(suf, off);
        if (lane + off < 64) suf += vsh;
      }
      uint32_t above = suf - Tl;  // total of lanes > lane
      uint32_t SS[4] = {s0 + above, s1 + above, s2 + above, s3 + above};
      uint32_t cc[4] = {c0, c1, c2, c3};
#pragma unroll
      for (int j = 0; j < 4; ++j) {
        if (SS[j] >= k_rem && (SS[j] - cc[j]) < k_rem) {
          scal[0] = (uint32_t)(lane * 4 + j);
          scal[1] = SS[j] - cc[j];  // count strictly greater (this level)
        }
      }
    }
    __syncthreads();
    uint32_t v = scal[0], g = scal[1];
    pfx |= (v << shift);
    maskHi |= (0xFFu << shift);
    k_rem -= g;
  }
  const uint32_t tb = pfx;  // exact bit pattern of the 256th largest

  // ---- compact candidates (bits >= tb) ----
  if (t == 0) scal[2] = 0;
  __syncthreads();
#pragma unroll
  for (int e = 0; e < 8; ++e) {
    if (bits[e] >= tb) {
      uint32_t pos = atomicAdd(&scal[2], 1u);
      if (pos < LIST_CAP)
        list[pos] = ((uint64_t)bits[e] << 32) |
                    (uint64_t)(uint32_t)(DI - 1 - (base + e));
    }
  }
  __syncthreads();
  int L = (int)scal[2];
  if (L > LIST_CAP) L = LIST_CAP;

  // ---- exact ranks among candidates (key includes stable index tiebreak) ----
  for (int sIdx = t; sIdx < L; sIdx += 256) {
    uint64_t key = list[sIdx];
    int rank = 0;
#pragma unroll 4
    for (int j = 0; j < L; ++j) rank += (int)(list[j] > key);
    if (rank < KTOP) {
      int idx = DI - 1 - (int)((uint32_t)key & 0xFFFFFFFFu);
      w_lds[idx] = OWA_C0 - OWA_C1 * (float)rank;
    }
  }
  __syncthreads();

  // ---- emit A[b,i] = w * mu * x as bf16 (coalesced 16B stores) ----
  u16x8 ov;
#pragma unroll
  for (int e = 0; e < 8; ++e) ov[e] = f2bf(w_lds[base + e] * muv[e] * xv[e]);
  *(u16x8*)(A + (size_t)row * DI + base) = ov;
}

// ---------------------------------------------------------------------------
// K2: out = relu(A @ W^T + bias); writes fp32 pre-BN out to y region and
// deterministic per-tile column sum / sumsq partials.
#define BM 128
#define BN 128
#define BKK 64

__global__ __launch_bounds__(256) void k_gemm(
    const ushort* __restrict__ A, const ushort* __restrict__ Wb,
    const float* __restrict__ bias, float* __restrict__ outp,
    float* __restrict__ psum, float* __restrict__ psumsq) {
  __shared__ __align__(16) ushort lA[BM * BKK];
  __shared__ __align__(16) ushort lB[BN * BKK];
  __shared__ float colsum[BN];
  __shared__ float colsq[BN];

  const int t = threadIdx.x;
  const int lane = t & 63;
  const int wv = t >> 6;
  const int wr = wv >> 1;
  const int wc = wv & 1;
  const int fr = lane & 15;
  const int kg = lane >> 4;

  // XCD-aware swizzle (2048 % 8 == 0, bijective)
  int bid = blockIdx.x;
  int orig = (bid & 7) * 256 + (bid >> 3);
  const int nb = orig & 15;
  const int mb = orig >> 4;
  const int m0 = mb * BM;
  const int n0 = nb * BN;

  f32x4 acc[4][4];
#pragma unroll
  for (int i = 0; i < 4; ++i)
#pragma unroll
    for (int j = 0; j < 4; ++j) acc[i][j] = (f32x4){0.f, 0.f, 0.f, 0.f};

  const int srow = wv * 8 + (lane >> 3);  // + i*32
  const int skel = (lane & 7) * 8;
  const ushort* gA = A + (size_t)(m0 + srow) * DI + skel;
  const ushort* gB = Wb + (size_t)(n0 + srow) * DI + skel;

  for (int kt = 0; kt < DI; kt += BKK) {
    const ushort* pa = gA + kt;
    const ushort* pb = gB + kt;
#pragma unroll
    for (int i = 0; i < 4; ++i) {
      gld_lds16(pa + (size_t)i * 32 * DI, lA + i * 2048 + wv * 512);
      gld_lds16(pb + (size_t)i * 32 * DI, lB + i * 2048 + wv * 512);
    }
    __syncthreads();
    const ushort* ra = lA + (wr * 64 + fr) * BKK + kg * 8;
    const ushort* rb = lB + (wc * 64 + fr) * BKK + kg * 8;
#pragma unroll
    for (int kk = 0; kk < BKK; kk += 32) {
      s16x8 af[4], bfr[4];
#pragma unroll
      for (int mi = 0; mi < 4; ++mi) af[mi] = *(const s16x8*)(ra + mi * 16 * BKK + kk);
#pragma unroll
      for (int ni = 0; ni < 4; ++ni) bfr[ni] = *(const s16x8*)(rb + ni * 16 * BKK + kk);
#pragma unroll
      for (int mi = 0; mi < 4; ++mi)
#pragma unroll
        for (int ni = 0; ni < 4; ++ni)
          acc[mi][ni] = __builtin_amdgcn_mfma_f32_16x16x32_bf16(
              af[mi], bfr[ni], acc[mi][ni], 0, 0, 0);
    }
    __syncthreads();
  }

  // epilogue: bias + relu + store + deterministic column partials
  if (t < BN) { colsum[t] = 0.f; colsq[t] = 0.f; }
  __syncthreads();
  const int orowbase = m0 + wr * 64 + kg * 4;
  const int ocolbase = n0 + wc * 64 + fr;
#pragma unroll
  for (int ni = 0; ni < 4; ++ni) {
    const int n = ocolbase + ni * 16;
    const float bv = bias[n];
    float cs = 0.f, cq = 0.f;
#pragma unroll
    for (int mi = 0; mi < 4; ++mi) {
      f32x4 v = acc[mi][ni];
#pragma unroll
      for (int r = 0; r < 4; ++r) {
        float zz = v[r] + bv;
        zz = fmaxf(zz, 0.f);
        outp[(size_t)(orowbase + mi * 16 + r) * DO + n] = zz;
        cs += zz;
        cq += zz * zz;
      }
    }
    cs += __shfl_xor(cs, 16); cq += __shfl_xor(cq, 16);
    cs += __shfl_xor(cs, 32); cq += __shfl_xor(cq, 32);
    if (kg == 0) {  // exactly 2 waves add per bin -> order-independent (a+b)
      atomicAdd(&colsum[wc * 64 + ni * 16 + fr], cs);
      atomicAdd(&colsq[wc * 64 + ni * 16 + fr], cq);
    }
  }
  __syncthreads();
  if (t < BN) {
    psum[(size_t)mb * DO + n0 + t] = colsum[t];
    psumsq[(size_t)mb * DO + n0 + t] = colsq[t];
  }
}

// ---------------------------------------------------------------------------
// K3: finalize BN scale/shift per column
__global__ __launch_bounds__(256) void k_bnfin(
    const float* __restrict__ psum, const float* __restrict__ psumsq,
    const float* __restrict__ gamma, const float* __restrict__ beta,
    float* __restrict__ scaleA, float* __restrict__ shiftA) {
  int n = blockIdx.x * 256 + threadIdx.x;
  float s = 0.f, q = 0.f;
  for (int r = 0; r < MT; ++r) {
    s += psum[(size_t)r * DO + n];
    q += psumsq[(size_t)r * DO + n];
  }
  float mean = s * (1.0f / (float)NB);
  float var = q * (1.0f / (float)NB) - mean * mean;
  var = fmaxf(var, 0.f);
  float rstd = rsqrtf(var + 1e-5f);
  float sc = gamma[n] * rstd;
  scaleA[n] = sc;
  shiftA[n] = beta[n] - mean * sc;
}

// ---------------------------------------------------------------------------
// K4: y = out*scale + shift, in place over the y region
__global__ __launch_bounds__(256) void k_bnapply(float* __restrict__ outp,
                                                 const float* __restrict__ scaleA,
                                                 const float* __restrict__ shiftA) {
  size_t i = ((size_t)blockIdx.x * 256 + threadIdx.x) * 4;
  int n = (int)(i & (DO - 1));
  float4 v = *(float4*)(outp + i);
  float4 sc = *(const float4*)(scaleA + n);
  float4 sh = *(const float4*)(shiftA + n);
  v.x = v.x * sc.x + sh.x;
  v.y = v.y * sc.y + sh.y;
  v.z = v.z * sc.z + sh.z;
  v.w = v.w * sc.w + sh.w;
  *(float4*)(outp + i) = v;
}

// ---------------------------------------------------------------------------
// K5 (small-ws fallback): recompute mu into the mu region
__global__ __launch_bounds__(256) void k_mu(const float* __restrict__ x,
                                            const float* __restrict__ center,
                                            const float* __restrict__ sharp,
                                            float* __restrict__ mu_out) {
  const int t = threadIdx.x;
  const int row = blockIdx.x;
  const int base = t * 8;
  const float* xr = x + (size_t)row * DI + base;
  float4 xa = *(const float4*)(xr);
  float4 xb = *(const float4*)(xr + 4);
  float4 ca = *(const float4*)(center + base);
  float4 cb = *(const float4*)(center + base + 4);
  float4 sa = *(const float4*)(sharp + base);
  float4 sb = *(const float4*)(sharp + base + 4);
  float xv[8] = {xa.x, xa.y, xa.z, xa.w, xb.x, xb.y, xb.z, xb.w};
  float cv[8] = {ca.x, ca.y, ca.z, ca.w, cb.x, cb.y, cb.z, cb.w};
  float sv[8] = {sa.x, sa.y, sa.z, sa.w, sb.x, sb.y, sb.z, sb.w};
  float mu[8];
#pragma unroll
  for (int e = 0; e < 8; ++e) {
    float s = sv[e] * (xv[e] - cv[e]);
    mu[e] = 1.0f / (1.0f + expf(-s));
  }
  float4 m0; m0.x = mu[0]; m0.y = mu[1]; m0.z = mu[2]; m0.w = mu[3];
  float4 m1; m1.x = mu[4]; m1.y = mu[5]; m1.z = mu[6]; m1.w = mu[7];
  *(float4*)(mu_out + (size_t)row * DI + base) = m0;
  *(float4*)(mu_out + (size_t)row * DI + base + 4) = m1;
}

// ---------------------------------------------------------------------------
extern "C" void kernel_launch(void* const* d_in, const int* in_sizes, int n_in,
                              void* d_out, int out_size, void* d_ws, size_t ws_size,
                              hipStream_t stream) {
  (void)in_sizes; (void)n_in; (void)out_size;
  const float* x = (const float*)d_in[0];
  const float* W = (const float*)d_in[1];
  const float* bias = (const float*)d_in[2];
  const float* center = (const float*)d_in[3];
  const float* sharp = (const float*)d_in[4];
  const float* gamma = (const float*)d_in[5];
  const float* beta = (const float*)d_in[6];
  // d_in[7] = top_k (always 256 per setup_inputs)

  float* outY = (float*)d_out;
  float* outMu = outY + (size_t)NB * DO;

  const size_t A_BYTES = (size_t)NB * DI * 2;
  const size_t WB_BYTES = (size_t)DO * DI * 2;
  const size_t PS_BYTES = (size_t)MT * DO * 4;
  const size_t SC_BYTES = (size_t)DO * 4;
  const size_t NEED_BIG = A_BYTES + WB_BYTES + 2 * PS_BYTES + 2 * SC_BYTES;

  char* p = (char*)d_ws;
  bool bigws = (ws_size >= NEED_BIG);
  ushort* A;
  if (bigws) { A = (ushort*)p; p += A_BYTES; }
  else       { A = (ushort*)outMu; }  // park bf16 A in mu region, recompute mu last
  ushort* Wb = (ushort*)p; p += WB_BYTES;
  float* psum = (float*)p; p += PS_BYTES;
  float* psumsq = (float*)p; p += PS_BYTES;
  float* scaleA = (float*)p; p += SC_BYTES;
  float* shiftA = (float*)p;

  k_cvt<<<dim3((DO * DI) / (256 * 8)), dim3(256), 0, stream>>>(W, Wb);
  k_topk<<<dim3(NB), dim3(256), 0, stream>>>(x, center, sharp,
                                             bigws ? outMu : (float*)nullptr, A);
  k_gemm<<<dim3((NB / BM) * (DO / BN)), dim3(256), 0, stream>>>(A, Wb, bias, outY,
                                                                psum, psumsq);
  k_bnfin<<<dim3(DO / 256), dim3(256), 0, stream>>>(psum, psumsq, gamma, beta,
                                                    scaleA, shiftA);
  k_bnapply<<<dim3((size_t)NB * DO / 4 / 256), dim3(256), 0, stream>>>(outY, scaleA,
                                                                       shiftA);
  if (!bigws) k_mu<<<dim3(NB), dim3(256), 0, stream>>>(x, center, sharp, outMu);
}

// Round 2
// 421.654 us; speedup vs baseline: 1.0878x; 1.0878x over previous
//
#include <hip/hip_runtime.h>
#include <stdint.h>

#define NB 16384       // batch rows
#define DI 2048        // d_in
#define DO 2048        // d_out
#define KTOP 256
#define LIST_CAP 384
#define MT (NB / 128)  // 128 row tiles for partial sums

typedef __attribute__((ext_vector_type(4))) float f32x4;
typedef __attribute__((ext_vector_type(8))) short s16x8;
typedef __attribute__((ext_vector_type(8))) unsigned short u16x8;

// OWA weights: w(rank) = (1 - 0.9*rank/255)/140.8
#define OWA_C0 7.10227273e-3f
#define OWA_C1 2.50668449e-5f

__device__ __forceinline__ ushort f2bf(float f) {
  uint32_t u = __float_as_uint(f);
  uint32_t r = (u + 0x7FFFu + ((u >> 16) & 1u)) >> 16;  // RNE
  return (ushort)r;
}

__device__ __forceinline__ void gld_lds16(const void* g, void* l) {
  __builtin_amdgcn_global_load_lds((__attribute__((address_space(1))) void*)g,
                                   (__attribute__((address_space(3))) void*)l,
                                   16, 0, 0);
}

// ---------------------------------------------------------------------------
// K0: convert W (fp32 [DO][DI]) -> bf16
__global__ __launch_bounds__(256) void k_cvt(const float* __restrict__ W,
                                             ushort* __restrict__ Wb) {
  size_t i = ((size_t)blockIdx.x * 256 + threadIdx.x) * 8;
  float4 a = *(const float4*)(W + i);
  float4 b = *(const float4*)(W + i + 4);
  u16x8 o;
  o[0] = f2bf(a.x); o[1] = f2bf(a.y); o[2] = f2bf(a.z); o[3] = f2bf(a.w);
  o[4] = f2bf(b.x); o[5] = f2bf(b.y); o[6] = f2bf(b.z); o[7] = f2bf(b.w);
  *(u16x8*)(Wb + i) = o;
}

// ---------------------------------------------------------------------------
// K1: per-row mu + top-k(256) OWA -> A (bf16). One block (256 thr) per row.
__global__ __launch_bounds__(256) void k_topk(
    const float* __restrict__ x, const float* __restrict__ center,
    const float* __restrict__ sharp, float* __restrict__ mu_out,
    ushort* __restrict__ A) {
  __shared__ __align__(16) float w_lds[DI];   // OWA weight per column (0 if not selected)
  __shared__ uint32_t histR[8 * 256];         // 8-way replicated histogram
  __shared__ uint64_t list[LIST_CAP];         // candidate keys (bits<<32 | (DI-1-idx))
  __shared__ uint32_t scal[4];

  const int t = threadIdx.x;
  const int lane = t & 63;
  const int wv = t >> 6;
  const int row = blockIdx.x;
  const int base = t * 8;

  const float* xr = x + (size_t)row * DI + base;
  float4 xa = *(const float4*)(xr);
  float4 xb = *(const float4*)(xr + 4);
  float4 ca = *(const float4*)(center + base);
  float4 cb = *(const float4*)(center + base + 4);
  float4 sa = *(const float4*)(sharp + base);
  float4 sb = *(const float4*)(sharp + base + 4);

  float xv[8] = {xa.x, xa.y, xa.z, xa.w, xb.x, xb.y, xb.z, xb.w};
  float cv[8] = {ca.x, ca.y, ca.z, ca.w, cb.x, cb.y, cb.z, cb.w};
  float sv[8] = {sa.x, sa.y, sa.z, sa.w, sb.x, sb.y, sb.z, sb.w};
  float muv[8];
  uint32_t bits[8];
#pragma unroll
  for (int e = 0; e < 8; ++e) {
    float s = sv[e] * (xv[e] - cv[e]);
    float m = 1.0f / (1.0f + expf(-s));
    muv[e] = m;
    bits[e] = __float_as_uint(m);  // mu>0 -> bit pattern is order-preserving
  }
  if (mu_out) {
    float4 m0; m0.x = muv[0]; m0.y = muv[1]; m0.z = muv[2]; m0.w = muv[3];
    float4 m1; m1.x = muv[4]; m1.y = muv[5]; m1.z = muv[6]; m1.w = muv[7];
    *(float4*)(mu_out + (size_t)row * DI + base) = m0;
    *(float4*)(mu_out + (size_t)row * DI + base + 4) = m1;
  }
  // zero weight array (scattered into much later; barriers in between)
  float4 z4; z4.x = z4.y = z4.z = z4.w = 0.f;
  *(float4*)(w_lds + base) = z4;
  *(float4*)(w_lds + base + 4) = z4;

  // ---- 4-pass byte radix select for the 256th-largest bit pattern ----
  uint32_t maskHi = 0, pfx = 0;
  uint32_t k_rem = KTOP;
  const uint32_t rep = (uint32_t)(t & 7) * 256u;
#pragma unroll 1
  for (int pass = 0; pass < 4; ++pass) {
    const int shift = 24 - pass * 8;
#pragma unroll
    for (int i = 0; i < 8; ++i) histR[t + 256 * i] = 0;
    __syncthreads();
#pragma unroll
    for (int e = 0; e < 8; ++e) {
      uint32_t bb = bits[e];
      if ((bb & maskHi) == pfx)
        atomicAdd(&histR[rep + ((bb >> shift) & 255u)], 1u);
    }
    __syncthreads();
    if (wv == 0) {  // single-wave suffix scan over 256 bins, no barriers
      uint32_t c0 = 0, c1 = 0, c2 = 0, c3 = 0;
#pragma unroll
      for (int r = 0; r < 8; ++r) {
        const uint32_t* h = &histR[r * 256 + lane * 4];
        c0 += h[0]; c1 += h[1]; c2 += h[2]; c3 += h[3];
      }
      uint32_t s3 = c3, s2 = c2 + s3, s1 = c1 + s2, s0 = c0 + s1;
      uint32_t Tl = s0, suf = s0;
#pragma unroll
      for (int off = 1; off < 64; off <<= 1) {
        uint32_t vsh = __shfl_down(suf, off);
        if (lane + off < 64) suf += vsh;
      }
      uint32_t above = suf - Tl;  // total of lanes > lane
      uint32_t SS[4] = {s0 + above, s1 + above, s2 + above, s3 + above};
      uint32_t cc[4] = {c0, c1, c2, c3};
#pragma unroll
      for (int j = 0; j < 4; ++j) {
        if (SS[j] >= k_rem && (SS[j] - cc[j]) < k_rem) {
          scal[0] = (uint32_t)(lane * 4 + j);
          scal[1] = SS[j] - cc[j];  // count strictly greater (this level)
        }
      }
    }
    __syncthreads();
    uint32_t v = scal[0], g = scal[1];
    pfx |= (v << shift);
    maskHi |= (0xFFu << shift);
    k_rem -= g;
  }
  const uint32_t tb = pfx;  // exact bit pattern of the 256th largest

  // ---- compact candidates (bits >= tb) ----
  if (t == 0) scal[2] = 0;
  __syncthreads();
#pragma unroll
  for (int e = 0; e < 8; ++e) {
    if (bits[e] >= tb) {
      uint32_t pos = atomicAdd(&scal[2], 1u);
      if (pos < LIST_CAP)
        list[pos] = ((uint64_t)bits[e] << 32) |
                    (uint64_t)(uint32_t)(DI - 1 - (base + e));
    }
  }
  __syncthreads();
  int L = (int)scal[2];
  if (L > LIST_CAP) L = LIST_CAP;

  // ---- exact ranks among candidates (key includes stable index tiebreak) ----
  for (int sIdx = t; sIdx < L; sIdx += 256) {
    uint64_t key = list[sIdx];
    int rank = 0;
#pragma unroll 4
    for (int j = 0; j < L; ++j) rank += (int)(list[j] > key);
    if (rank < KTOP) {
      int idx = DI - 1 - (int)((uint32_t)key & 0xFFFFFFFFu);
      w_lds[idx] = OWA_C0 - OWA_C1 * (float)rank;
    }
  }
  __syncthreads();

  // ---- emit A[b,i] = w * mu * x as bf16 (coalesced 16B stores) ----
  u16x8 ov;
#pragma unroll
  for (int e = 0; e < 8; ++e) ov[e] = f2bf(w_lds[base + e] * muv[e] * xv[e]);
  *(u16x8*)(A + (size_t)row * DI + base) = ov;
}

// ---------------------------------------------------------------------------
// K2: out = relu(A @ W^T + bias); writes fp32 pre-BN out to y region and
// deterministic per-tile column sum / sumsq partials.
//
// T2 bank-conflict fix (rule #21: both-sides-or-neither with global_load_lds):
// LDS dest stays LINEAR; the 16B chunk index within each 128B row is
// XOR-swizzled by (row&7) on the GLOBAL source address at staging, and the
// same XOR is applied on the ds_read_b128 address. Each 16-lane read phase
// then spreads over 8 distinct 16B slots (2 lanes/slot = free) instead of
// all 16 lanes on one slot (16-way conflict, the R1 5e7 counter).
#define BM 128
#define BN 128
#define BKK 64

__global__ __launch_bounds__(256) void k_gemm(
    const ushort* __restrict__ A, const ushort* __restrict__ Wb,
    const float* __restrict__ bias, float* __restrict__ outp,
    float* __restrict__ psum, float* __restrict__ psumsq) {
  __shared__ __align__(16) ushort lA[BM * BKK];
  __shared__ __align__(16) ushort lB[BN * BKK];
  __shared__ float colsum[BN];
  __shared__ float colsq[BN];

  const int t = threadIdx.x;
  const int lane = t & 63;
  const int wv = t >> 6;
  const int wr = wv >> 1;
  const int wc = wv & 1;
  const int fr = lane & 15;
  const int kg = lane >> 4;

  // XCD-aware swizzle (2048 % 8 == 0, bijective)
  int bid = blockIdx.x;
  int orig = (bid & 7) * 256 + (bid >> 3);
  const int nb = orig & 15;
  const int mb = orig >> 4;
  const int m0 = mb * BM;
  const int n0 = nb * BN;

  f32x4 acc[4][4];
#pragma unroll
  for (int i = 0; i < 4; ++i)
#pragma unroll
    for (int j = 0; j < 4; ++j) acc[i][j] = (f32x4){0.f, 0.f, 0.f, 0.f};

  // staging: wave wv writes rows wv*8+(lane>>3) (+i*32), LDS dest linear.
  // source chunk pre-swizzled: chunk ^= (row&7) == (lane>>3)&7
  const int srow = wv * 8 + (lane >> 3);  // + i*32
  const int skel = (((lane & 7) ^ ((lane >> 3) & 7)) * 8);
  const ushort* gA = A + (size_t)(m0 + srow) * DI + skel;
  const ushort* gB = Wb + (size_t)(n0 + srow) * DI + skel;

  const int s = fr & 7;  // row&7 of every fragment row this lane reads
  const ushort* ra = lA + (wr * 64 + fr) * BKK;
  const ushort* rb = lB + (wc * 64 + fr) * BKK;

  for (int kt = 0; kt < DI; kt += BKK) {
    const ushort* pa = gA + kt;
    const ushort* pb = gB + kt;
#pragma unroll
    for (int i = 0; i < 4; ++i) {
      gld_lds16(pa + (size_t)i * 32 * DI, lA + i * 2048 + wv * 512);
      gld_lds16(pb + (size_t)i * 32 * DI, lB + i * 2048 + wv * 512);
    }
    __syncthreads();
#pragma unroll
    for (int kh = 0; kh < 2; ++kh) {  // K halves: chunk base c4 = kh*4
      const int coff = (((kg + kh * 4) ^ s) * 8);  // swizzled read chunk
      s16x8 af[4], bfr[4];
#pragma unroll
      for (int mi = 0; mi < 4; ++mi)
        af[mi] = *(const s16x8*)(ra + mi * 16 * BKK + coff);
#pragma unroll
      for (int ni = 0; ni < 4; ++ni)
        bfr[ni] = *(const s16x8*)(rb + ni * 16 * BKK + coff);
#pragma unroll
      for (int mi = 0; mi < 4; ++mi)
#pragma unroll
        for (int ni = 0; ni < 4; ++ni)
          acc[mi][ni] = __builtin_amdgcn_mfma_f32_16x16x32_bf16(
              af[mi], bfr[ni], acc[mi][ni], 0, 0, 0);
    }
    __syncthreads();
  }

  // epilogue: bias + relu + store + deterministic column partials
  if (t < BN) { colsum[t] = 0.f; colsq[t] = 0.f; }
  __syncthreads();
  const int orowbase = m0 + wr * 64 + kg * 4;
  const int ocolbase = n0 + wc * 64 + fr;
#pragma unroll
  for (int ni = 0; ni < 4; ++ni) {
    const int n = ocolbase + ni * 16;
    const float bv = bias[n];
    float cs = 0.f, cq = 0.f;
#pragma unroll
    for (int mi = 0; mi < 4; ++mi) {
      f32x4 v = acc[mi][ni];
#pragma unroll
      for (int r = 0; r < 4; ++r) {
        float zz = v[r] + bv;
        zz = fmaxf(zz, 0.f);
        outp[(size_t)(orowbase + mi * 16 + r) * DO + n] = zz;
        cs += zz;
        cq += zz * zz;
      }
    }
    cs += __shfl_xor(cs, 16); cq += __shfl_xor(cq, 16);
    cs += __shfl_xor(cs, 32); cq += __shfl_xor(cq, 32);
    if (kg == 0) {  // exactly 2 waves add per bin -> order-independent (a+b)
      atomicAdd(&colsum[wc * 64 + ni * 16 + fr], cs);
      atomicAdd(&colsq[wc * 64 + ni * 16 + fr], cq);
    }
  }
  __syncthreads();
  if (t < BN) {
    psum[(size_t)mb * DO + n0 + t] = colsum[t];
    psumsq[(size_t)mb * DO + n0 + t] = colsq[t];
  }
}

// ---------------------------------------------------------------------------
// K3: finalize BN scale/shift per column
__global__ __launch_bounds__(256) void k_bnfin(
    const float* __restrict__ psum, const float* __restrict__ psumsq,
    const float* __restrict__ gamma, const float* __restrict__ beta,
    float* __restrict__ scaleA, float* __restrict__ shiftA) {
  int n = blockIdx.x * 256 + threadIdx.x;
  float s = 0.f, q = 0.f;
  for (int r = 0; r < MT; ++r) {
    s += psum[(size_t)r * DO + n];
    q += psumsq[(size_t)r * DO + n];
  }
  float mean = s * (1.0f / (float)NB);
  float var = q * (1.0f / (float)NB) - mean * mean;
  var = fmaxf(var, 0.f);
  float rstd = rsqrtf(var + 1e-5f);
  float sc = gamma[n] * rstd;
  scaleA[n] = sc;
  shiftA[n] = beta[n] - mean * sc;
}

// ---------------------------------------------------------------------------
// K4: y = out*scale + shift, in place over the y region
__global__ __launch_bounds__(256) void k_bnapply(float* __restrict__ outp,
                                                 const float* __restrict__ scaleA,
                                                 const float* __restrict__ shiftA) {
  size_t i = ((size_t)blockIdx.x * 256 + threadIdx.x) * 4;
  int n = (int)(i & (DO - 1));
  float4 v = *(float4*)(outp + i);
  float4 sc = *(const float4*)(scaleA + n);
  float4 sh = *(const float4*)(shiftA + n);
  v.x = v.x * sc.x + sh.x;
  v.y = v.y * sc.y + sh.y;
  v.z = v.z * sc.z + sh.z;
  v.w = v.w * sc.w + sh.w;
  *(float4*)(outp + i) = v;
}

// ---------------------------------------------------------------------------
// K5 (small-ws fallback): recompute mu into the mu region
__global__ __launch_bounds__(256) void k_mu(const float* __restrict__ x,
                                            const float* __restrict__ center,
                                            const float* __restrict__ sharp,
                                            float* __restrict__ mu_out) {
  const int t = threadIdx.x;
  const int row = blockIdx.x;
  const int base = t * 8;
  const float* xr = x + (size_t)row * DI + base;
  float4 xa = *(const float4*)(xr);
  float4 xb = *(const float4*)(xr + 4);
  float4 ca = *(const float4*)(center + base);
  float4 cb = *(const float4*)(center + base + 4);
  float4 sa = *(const float4*)(sharp + base);
  float4 sb = *(const float4*)(sharp + base + 4);
  float xv[8] = {xa.x, xa.y, xa.z, xa.w, xb.x, xb.y, xb.z, xb.w};
  float cv[8] = {ca.x, ca.y, ca.z, ca.w, cb.x, cb.y, cb.z, cb.w};
  float sv[8] = {sa.x, sa.y, sa.z, sa.w, sb.x, sb.y, sb.z, sb.w};
  float mu[8];
#pragma unroll
  for (int e = 0; e < 8; ++e) {
    float s = sv[e] * (xv[e] - cv[e]);
    mu[e] = 1.0f / (1.0f + expf(-s));
  }
  float4 m0; m0.x = mu[0]; m0.y = mu[1]; m0.z = mu[2]; m0.w = mu[3];
  float4 m1; m1.x = mu[4]; m1.y = mu[5]; m1.z = mu[6]; m1.w = mu[7];
  *(float4*)(mu_out + (size_t)row * DI + base) = m0;
  *(float4*)(mu_out + (size_t)row * DI + base + 4) = m1;
}

// ---------------------------------------------------------------------------
extern "C" void kernel_launch(void* const* d_in, const int* in_sizes, int n_in,
                              void* d_out, int out_size, void* d_ws, size_t ws_size,
                              hipStream_t stream) {
  (void)in_sizes; (void)n_in; (void)out_size;
  const float* x = (const float*)d_in[0];
  const float* W = (const float*)d_in[1];
  const float* bias = (const float*)d_in[2];
  const float* center = (const float*)d_in[3];
  const float* sharp = (const float*)d_in[4];
  const float* gamma = (const float*)d_in[5];
  const float* beta = (const float*)d_in[6];
  // d_in[7] = top_k (always 256 per setup_inputs)

  float* outY = (float*)d_out;
  float* outMu = outY + (size_t)NB * DO;

  const size_t A_BYTES = (size_t)NB * DI * 2;
  const size_t WB_BYTES = (size_t)DO * DI * 2;
  const size_t PS_BYTES = (size_t)MT * DO * 4;
  const size_t SC_BYTES = (size_t)DO * 4;
  const size_t NEED_BIG = A_BYTES + WB_BYTES + 2 * PS_BYTES + 2 * SC_BYTES;

  char* p = (char*)d_ws;
  bool bigws = (ws_size >= NEED_BIG);
  ushort* A;
  if (bigws) { A = (ushort*)p; p += A_BYTES; }
  else       { A = (ushort*)outMu; }  // park bf16 A in mu region, recompute mu last
  ushort* Wb = (ushort*)p; p += WB_BYTES;
  float* psum = (float*)p; p += PS_BYTES;
  float* psumsq = (float*)p; p += PS_BYTES;
  float* scaleA = (float*)p; p += SC_BYTES;
  float* shiftA = (float*)p;

  k_cvt<<<dim3((DO * DI) / (256 * 8)), dim3(256), 0, stream>>>(W, Wb);
  k_topk<<<dim3(NB), dim3(256), 0, stream>>>(x, center, sharp,
                                             bigws ? outMu : (float*)nullptr, A);
  k_gemm<<<dim3((NB / BM) * (DO / BN)), dim3(256), 0, stream>>>(A, Wb, bias, outY,
                                                                psum, psumsq);
  k_bnfin<<<dim3(DO / 256), dim3(256), 0, stream>>>(psum, psumsq, gamma, beta,
                                                    scaleA, shiftA);
  k_bnapply<<<dim3((size_t)NB * DO / 4 / 256), dim3(256), 0, stream>>>(outY, scaleA,
                                                                       shiftA);
  if (!bigws) k_mu<<<dim3(NB), dim3(256), 0, stream>>>(x, center, sharp, outMu);
}

// Round 3
// 395.084 us; speedup vs baseline: 1.1609x; 1.0673x over previous
//
#include <hip/hip_runtime.h>
#include <stdint.h>

#define NB 16384       // batch rows
#define DI 2048        // d_in
#define DO 2048        // d_out
#define KTOP 256
#define LIST_CAP 384
#define MT (NB / 256)  // 256-row tiles for partial sums (64)

typedef __attribute__((ext_vector_type(4))) float f32x4;
typedef __attribute__((ext_vector_type(8))) short s16x8;
typedef __attribute__((ext_vector_type(8))) unsigned short u16x8;

// OWA weights: w(rank) = (1 - 0.9*rank/255)/140.8
#define OWA_C0 7.10227273e-3f
#define OWA_C1 2.50668449e-5f

__device__ __forceinline__ ushort f2bf(float f) {
  uint32_t u = __float_as_uint(f);
  uint32_t r = (u + 0x7FFFu + ((u >> 16) & 1u)) >> 16;  // RNE
  return (ushort)r;
}

__device__ __forceinline__ void gld_lds16(const void* g, void* l) {
  __builtin_amdgcn_global_load_lds((__attribute__((address_space(1))) void*)g,
                                   (__attribute__((address_space(3))) void*)l,
                                   16, 0, 0);
}

// ---------------------------------------------------------------------------
// K0: convert W (fp32 [DO][DI]) -> bf16
__global__ __launch_bounds__(256) void k_cvt(const float* __restrict__ W,
                                             ushort* __restrict__ Wb) {
  size_t i = ((size_t)blockIdx.x * 256 + threadIdx.x) * 8;
  float4 a = *(const float4*)(W + i);
  float4 b = *(const float4*)(W + i + 4);
  u16x8 o;
  o[0] = f2bf(a.x); o[1] = f2bf(a.y); o[2] = f2bf(a.z); o[3] = f2bf(a.w);
  o[4] = f2bf(b.x); o[5] = f2bf(b.y); o[6] = f2bf(b.z); o[7] = f2bf(b.w);
  *(u16x8*)(Wb + i) = o;
}

// ---------------------------------------------------------------------------
// K1: per-row mu + top-k(256) OWA -> A (bf16). One block (256 thr) per row.
__global__ __launch_bounds__(256) void k_topk(
    const float* __restrict__ x, const float* __restrict__ center,
    const float* __restrict__ sharp, float* __restrict__ mu_out,
    ushort* __restrict__ A) {
  __shared__ __align__(16) float w_lds[DI];   // OWA weight per column (0 if not selected)
  __shared__ uint32_t histR[8 * 256];         // 8-way replicated histogram
  __shared__ uint64_t list[LIST_CAP];         // candidate keys (bits<<32 | (DI-1-idx))
  __shared__ uint32_t scal[4];

  const int t = threadIdx.x;
  const int lane = t & 63;
  const int wv = t >> 6;
  const int row = blockIdx.x;
  const int base = t * 8;

  const float* xr = x + (size_t)row * DI + base;
  float4 xa = *(const float4*)(xr);
  float4 xb = *(const float4*)(xr + 4);
  float4 ca = *(const float4*)(center + base);
  float4 cb = *(const float4*)(center + base + 4);
  float4 sa = *(const float4*)(sharp + base);
  float4 sb = *(const float4*)(sharp + base + 4);

  float xv[8] = {xa.x, xa.y, xa.z, xa.w, xb.x, xb.y, xb.z, xb.w};
  float cv[8] = {ca.x, ca.y, ca.z, ca.w, cb.x, cb.y, cb.z, cb.w};
  float sv[8] = {sa.x, sa.y, sa.z, sa.w, sb.x, sb.y, sb.z, sb.w};
  float muv[8];
  uint32_t bits[8];
#pragma unroll
  for (int e = 0; e < 8; ++e) {
    float s = sv[e] * (xv[e] - cv[e]);
    float m = 1.0f / (1.0f + expf(-s));
    muv[e] = m;
    bits[e] = __float_as_uint(m);  // mu>0 -> bit pattern is order-preserving
  }
  if (mu_out) {
    float4 m0; m0.x = muv[0]; m0.y = muv[1]; m0.z = muv[2]; m0.w = muv[3];
    float4 m1; m1.x = muv[4]; m1.y = muv[5]; m1.z = muv[6]; m1.w = muv[7];
    *(float4*)(mu_out + (size_t)row * DI + base) = m0;
    *(float4*)(mu_out + (size_t)row * DI + base + 4) = m1;
  }
  // zero weight array (scattered into much later; barriers in between)
  float4 z4; z4.x = z4.y = z4.z = z4.w = 0.f;
  *(float4*)(w_lds + base) = z4;
  *(float4*)(w_lds + base + 4) = z4;

  // ---- 4-pass byte radix select for the 256th-largest bit pattern ----
  uint32_t maskHi = 0, pfx = 0;
  uint32_t k_rem = KTOP;
  const uint32_t rep = (uint32_t)(t & 7) * 256u;
#pragma unroll 1
  for (int pass = 0; pass < 4; ++pass) {
    const int shift = 24 - pass * 8;
#pragma unroll
    for (int i = 0; i < 8; ++i) histR[t + 256 * i] = 0;
    __syncthreads();
#pragma unroll
    for (int e = 0; e < 8; ++e) {
      uint32_t bb = bits[e];
      if ((bb & maskHi) == pfx)
        atomicAdd(&histR[rep + ((bb >> shift) & 255u)], 1u);
    }
    __syncthreads();
    if (wv == 0) {  // single-wave suffix scan over 256 bins, no barriers
      uint32_t c0 = 0, c1 = 0, c2 = 0, c3 = 0;
#pragma unroll
      for (int r = 0; r < 8; ++r) {
        const uint32_t* h = &histR[r * 256 + lane * 4];
        c0 += h[0]; c1 += h[1]; c2 += h[2]; c3 += h[3];
      }
      uint32_t s3 = c3, s2 = c2 + s3, s1 = c1 + s2, s0 = c0 + s1;
      uint32_t Tl = s0, suf = s0;
#pragma unroll
      for (int off = 1; off < 64; off <<= 1) {
        uint32_t vsh = __shfl_down(suf, off);
        if (lane + off < 64) suf += vsh;
      }
      uint32_t above = suf - Tl;  // total of lanes > lane
      uint32_t SS[4] = {s0 + above, s1 + above, s2 + above, s3 + above};
      uint32_t cc[4] = {c0, c1, c2, c3};
#pragma unroll
      for (int j = 0; j < 4; ++j) {
        if (SS[j] >= k_rem && (SS[j] - cc[j]) < k_rem) {
          scal[0] = (uint32_t)(lane * 4 + j);
          scal[1] = SS[j] - cc[j];  // count strictly greater (this level)
        }
      }
    }
    __syncthreads();
    uint32_t v = scal[0], g = scal[1];
    pfx |= (v << shift);
    maskHi |= (0xFFu << shift);
    k_rem -= g;
  }
  const uint32_t tb = pfx;  // exact bit pattern of the 256th largest

  // ---- compact candidates (bits >= tb) ----
  if (t == 0) scal[2] = 0;
  __syncthreads();
#pragma unroll
  for (int e = 0; e < 8; ++e) {
    if (bits[e] >= tb) {
      uint32_t pos = atomicAdd(&scal[2], 1u);
      if (pos < LIST_CAP)
        list[pos] = ((uint64_t)bits[e] << 32) |
                    (uint64_t)(uint32_t)(DI - 1 - (base + e));
    }
  }
  __syncthreads();
  int L = (int)scal[2];
  if (L > LIST_CAP) L = LIST_CAP;

  // ---- exact ranks among candidates (key includes stable index tiebreak) ----
  for (int sIdx = t; sIdx < L; sIdx += 256) {
    uint64_t key = list[sIdx];
    int rank = 0;
#pragma unroll 4
    for (int j = 0; j < L; ++j) rank += (int)(list[j] > key);
    if (rank < KTOP) {
      int idx = DI - 1 - (int)((uint32_t)key & 0xFFFFFFFFu);
      w_lds[idx] = OWA_C0 - OWA_C1 * (float)rank;
    }
  }
  __syncthreads();

  // ---- emit A[b,i] = w * mu * x as bf16 (coalesced 16B stores) ----
  u16x8 ov;
#pragma unroll
  for (int e = 0; e < 8; ++e) ov[e] = f2bf(w_lds[base + e] * muv[e] * xv[e]);
  *(u16x8*)(A + (size_t)row * DI + base) = ov;
}

// ---------------------------------------------------------------------------
// K2: 256x256x64 8-phase pipelined GEMM (T2+T3+T4+T5).
// out = relu(A @ W^T + bias), fp32 out + deterministic per-tile column
// sum/sumsq partials.
//
// LDS: 4 half-slots per matrix (128x64 bf16 = 16 KB each) = ring double-buffer
// at half-tile granularity (parity (T&1)). Chunk-XOR swizzle (R2, 0-conflict):
// LDS[row][ch] = global[row][ch ^ (row&7)], read with same XOR.
//
// Stage schedule (1 half-tile = 2 global_load_lds/thread per phase):
//   (T,0): A-half0 of T+1   (A parity-(T+1) slots last read at (T-1,3))
//   (T,1): A-half1 of T+1
//   (T,2): B-half0 of T+2   (B parity-T slots only read at (T,0))
//   (T,3): B-half1 of T+2, then vmcnt(4) -> A(T+1),B(T+1) landed, newest
//          2 stages (B of T+2) stay in flight; end-barrier publishes to all
//          waves before (T+1,0)'s ds_reads. Epilogue: T=30 vmcnt(0).
#define HALFS 8192  // ushorts per half-slot (128 rows x 64 cols)

#define STAGE_A(U, h)                                             \
  do {                                                            \
    ushort* sl = lA + (((((U) & 1) << 1) + (h)) * HALFS);         \
    gld_lds16(pA[h][0] + (size_t)(U) * 64, sl + d0);              \
    gld_lds16(pA[h][1] + (size_t)(U) * 64, sl + d1);              \
  } while (0)

#define STAGE_B(U, h)                                             \
  do {                                                            \
    ushort* sl = lB + (((((U) & 1) << 1) + (h)) * HALFS);         \
    gld_lds16(pB[h][0] + (size_t)(U) * 64, sl + d0);              \
    gld_lds16(pB[h][1] + (size_t)(U) * 64, sl + d1);              \
  } while (0)

#define MFMA_PHASE(q, A00, A01, A10, A11)                                      \
  do {                                                                         \
    __builtin_amdgcn_s_setprio(1);                                             \
    _Pragma("unroll") for (int ni = 0; ni < 4; ++ni) {                         \
      acc[2 * (q)][ni] = __builtin_amdgcn_mfma_f32_16x16x32_bf16(              \
          A00, breg[ni][0], acc[2 * (q)][ni], 0, 0, 0);                        \
      acc[2 * (q)][ni] = __builtin_amdgcn_mfma_f32_16x16x32_bf16(              \
          A01, breg[ni][1], acc[2 * (q)][ni], 0, 0, 0);                        \
      acc[2 * (q) + 1][ni] = __builtin_amdgcn_mfma_f32_16x16x32_bf16(          \
          A10, breg[ni][0], acc[2 * (q) + 1][ni], 0, 0, 0);                    \
      acc[2 * (q) + 1][ni] = __builtin_amdgcn_mfma_f32_16x16x32_bf16(          \
          A11, breg[ni][1], acc[2 * (q) + 1][ni], 0, 0, 0);                    \
    }                                                                          \
    __builtin_amdgcn_s_setprio(0);                                             \
  } while (0)

#define PHASE(q, STAGE_STMT, TAIL_STMT)                                        \
  do {                                                                         \
    s16x8 a00 = *(const s16x8*)(sAp + (32 * (q)) * 64 + aoff + c0);            \
    s16x8 a01 = *(const s16x8*)(sAp + (32 * (q)) * 64 + aoff + c1);            \
    s16x8 a10 = *(const s16x8*)(sAp + (32 * (q) + 16) * 64 + aoff + c0);       \
    s16x8 a11 = *(const s16x8*)(sAp + (32 * (q) + 16) * 64 + aoff + c1);       \
    STAGE_STMT;                                                                \
    __builtin_amdgcn_s_barrier();                                              \
    asm volatile("s_waitcnt lgkmcnt(0)" ::: "memory");                         \
    __builtin_amdgcn_sched_barrier(0);                                         \
    MFMA_PHASE(q, a00, a01, a10, a11);                                         \
    TAIL_STMT;                                                                 \
    __builtin_amdgcn_s_barrier();                                              \
  } while (0)

__global__ __launch_bounds__(512, 2) void k_gemm(
    const ushort* __restrict__ A, const ushort* __restrict__ Wb,
    const float* __restrict__ bias, float* __restrict__ outp,
    float* __restrict__ psum, float* __restrict__ psumsq) {
  __shared__ __align__(16) ushort lA[4 * HALFS];
  __shared__ __align__(16) ushort lB[4 * HALFS];

  const int t = threadIdx.x;
  const int lane = t & 63;
  const int wv = t >> 6;
  const int wm = wv >> 2;   // 0..1: which 128-row half of the M tile
  const int wn = wv & 3;    // 0..3: which 64-col strip of the N tile
  const int fr = lane & 15;
  const int kg = lane >> 4;
  const int s = fr & 7;

  // XCD-aware bijective swizzle (512 blocks, 512 % 8 == 0)
  int bid = blockIdx.x;
  int orig = (bid & 7) * 64 + (bid >> 3);
  const int nb = orig & 7;
  const int mb = orig >> 3;
  const int m0 = mb * 256;
  const int n0 = nb * 256;

  // staging address precompute: per thread, loads i=0,1 cover rows
  // i*64 + (t>>3), chunk t&7 (chunk pre-swizzled by row&7 on global src)
  const int srow0 = t >> 3;
  const int scol = ((t & 7) ^ (srow0 & 7)) * 8;
  const ushort* pA[2][2];
  const ushort* pB[2][2];
#pragma unroll
  for (int h = 0; h < 2; ++h) {
#pragma unroll
    for (int i = 0; i < 2; ++i) {
      pA[h][i] = A + (size_t)(m0 + h * 128 + i * 64 + srow0) * DI + scol;
      pB[h][i] = Wb + (size_t)(n0 + h * 128 + i * 64 + srow0) * DI + scol;
    }
  }
  const int d0 = t * 8;          // LDS dst (ushorts) for load 0
  const int d1 = (512 + t) * 8;  // load 1

  f32x4 acc[8][4];
#pragma unroll
  for (int i = 0; i < 8; ++i)
#pragma unroll
    for (int j = 0; j < 4; ++j) acc[i][j] = (f32x4){0.f, 0.f, 0.f, 0.f};

  // prologue: B(0), A(0), B(1); leave B(1) (4 loads) in flight
  STAGE_B(0, 0); STAGE_B(0, 1);
  STAGE_A(0, 0); STAGE_A(0, 1);
  STAGE_B(1, 0); STAGE_B(1, 1);
  asm volatile("s_waitcnt vmcnt(4)" ::: "memory");
  __builtin_amdgcn_s_barrier();

  // fragment read offsets (ushorts)
  const int aoff = fr * 64;
  const int c0 = (kg ^ s) * 8;
  const int c1 = ((4 + kg) ^ s) * 8;
  const int boff = ((wn & 1) * 64 + fr) * 64;

  s16x8 breg[4][2];

#pragma unroll 1
  for (int T = 0; T < 32; ++T) {
    const ushort* sAp = lA + (((T & 1) << 1) + wm) * HALFS;
    const ushort* sBp = lB + (((T & 1) << 1) + (wn >> 1)) * HALFS;

#pragma unroll
    for (int ni = 0; ni < 4; ++ni) {
      breg[ni][0] = *(const s16x8*)(sBp + ni * 1024 + boff + c0);
      breg[ni][1] = *(const s16x8*)(sBp + ni * 1024 + boff + c1);
    }
    PHASE(0, if (T < 31) STAGE_A(T + 1, 0), );
    PHASE(1, if (T < 31) STAGE_A(T + 1, 1), );
    PHASE(2, if (T < 30) STAGE_B(T + 2, 0), );
    PHASE(3, if (T < 30) STAGE_B(T + 2, 1),
          if (T < 30) { asm volatile("s_waitcnt vmcnt(4)" ::: "memory"); }
          else if (T == 30) { asm volatile("s_waitcnt vmcnt(0)" ::: "memory"); });
  }

  // epilogue: bias + relu + store + deterministic column partials
  __syncthreads();
  float* colsum = (float*)lA;     // reuse tile LDS
  float* colsq = colsum + 256;
  if (t < 256) { colsum[t] = 0.f; colsq[t] = 0.f; }
  __syncthreads();
#pragma unroll
  for (int ni = 0; ni < 4; ++ni) {
    const int n = n0 + wn * 64 + ni * 16 + fr;
    const float bv = bias[n];
    float cs = 0.f, cq = 0.f;
#pragma unroll
    for (int mi = 0; mi < 8; ++mi) {
      f32x4 v = acc[mi][ni];
#pragma unroll
      for (int r = 0; r < 4; ++r) {
        float zz = fmaxf(v[r] + bv, 0.f);
        outp[(size_t)(m0 + wm * 128 + mi * 16 + kg * 4 + r) * DO + n] = zz;
        cs += zz;
        cq += zz * zz;
      }
    }
    cs += __shfl_xor(cs, 16); cq += __shfl_xor(cq, 16);
    cs += __shfl_xor(cs, 32); cq += __shfl_xor(cq, 32);
    if (kg == 0) {  // exactly 2 waves (wm=0,1) add per column bin
      atomicAdd(&colsum[wn * 64 + ni * 16 + fr], cs);
      atomicAdd(&colsq[wn * 64 + ni * 16 + fr], cq);
    }
  }
  __syncthreads();
  if (t < 256) {
    psum[(size_t)mb * DO + n0 + t] = colsum[t];
    psumsq[(size_t)mb * DO + n0 + t] = colsq[t];
  }
}

// ---------------------------------------------------------------------------
// K3: finalize BN scale/shift per column
__global__ __launch_bounds__(256) void k_bnfin(
    const float* __restrict__ psum, const float* __restrict__ psumsq,
    const float* __restrict__ gamma, const float* __restrict__ beta,
    float* __restrict__ scaleA, float* __restrict__ shiftA) {
  int n = blockIdx.x * 256 + threadIdx.x;
  float s = 0.f, q = 0.f;
  for (int r = 0; r < MT; ++r) {
    s += psum[(size_t)r * DO + n];
    q += psumsq[(size_t)r * DO + n];
  }
  float mean = s * (1.0f / (float)NB);
  float var = q * (1.0f / (float)NB) - mean * mean;
  var = fmaxf(var, 0.f);
  float rstd = rsqrtf(var + 1e-5f);
  float sc = gamma[n] * rstd;
  scaleA[n] = sc;
  shiftA[n] = beta[n] - mean * sc;
}

// ---------------------------------------------------------------------------
// K4: y = out*scale + shift, in place over the y region
__global__ __launch_bounds__(256) void k_bnapply(float* __restrict__ outp,
                                                 const float* __restrict__ scaleA,
                                                 const float* __restrict__ shiftA) {
  size_t i = ((size_t)blockIdx.x * 256 + threadIdx.x) * 4;
  int n = (int)(i & (DO - 1));
  float4 v = *(float4*)(outp + i);
  float4 sc = *(const float4*)(scaleA + n);
  float4 sh = *(const float4*)(shiftA + n);
  v.x = v.x * sc.x + sh.x;
  v.y = v.y * sc.y + sh.y;
  v.z = v.z * sc.z + sh.z;
  v.w = v.w * sc.w + sh.w;
  *(float4*)(outp + i) = v;
}

// ---------------------------------------------------------------------------
// K5 (small-ws fallback): recompute mu into the mu region
__global__ __launch_bounds__(256) void k_mu(const float* __restrict__ x,
                                            const float* __restrict__ center,
                                            const float* __restrict__ sharp,
                                            float* __restrict__ mu_out) {
  const int t = threadIdx.x;
  const int row = blockIdx.x;
  const int base = t * 8;
  const float* xr = x + (size_t)row * DI + base;
  float4 xa = *(const float4*)(xr);
  float4 xb = *(const float4*)(xr + 4);
  float4 ca = *(const float4*)(center + base);
  float4 cb = *(const float4*)(center + base + 4);
  float4 sa = *(const float4*)(sharp + base);
  float4 sb = *(const float4*)(sharp + base + 4);
  float xv[8] = {xa.x, xa.y, xa.z, xa.w, xb.x, xb.y, xb.z, xb.w};
  float cv[8] = {ca.x, ca.y, ca.z, ca.w, cb.x, cb.y, cb.z, cb.w};
  float sv[8] = {sa.x, sa.y, sa.z, sa.w, sb.x, sb.y, sb.z, sb.w};
  float mu[8];
#pragma unroll
  for (int e = 0; e < 8; ++e) {
    float s = sv[e] * (xv[e] - cv[e]);
    mu[e] = 1.0f / (1.0f + expf(-s));
  }
  float4 m0; m0.x = mu[0]; m0.y = mu[1]; m0.z = mu[2]; m0.w = mu[3];
  float4 m1; m1.x = mu[4]; m1.y = mu[5]; m1.z = mu[6]; m1.w = mu[7];
  *(float4*)(mu_out + (size_t)row * DI + base) = m0;
  *(float4*)(mu_out + (size_t)row * DI + base + 4) = m1;
}

// ---------------------------------------------------------------------------
extern "C" void kernel_launch(void* const* d_in, const int* in_sizes, int n_in,
                              void* d_out, int out_size, void* d_ws, size_t ws_size,
                              hipStream_t stream) {
  (void)in_sizes; (void)n_in; (void)out_size;
  const float* x = (const float*)d_in[0];
  const float* W = (const float*)d_in[1];
  const float* bias = (const float*)d_in[2];
  const float* center = (const float*)d_in[3];
  const float* sharp = (const float*)d_in[4];
  const float* gamma = (const float*)d_in[5];
  const float* beta = (const float*)d_in[6];
  // d_in[7] = top_k (always 256 per setup_inputs)

  float* outY = (float*)d_out;
  float* outMu = outY + (size_t)NB * DO;

  const size_t A_BYTES = (size_t)NB * DI * 2;
  const size_t WB_BYTES = (size_t)DO * DI * 2;
  const size_t PS_BYTES = (size_t)MT * DO * 4;
  const size_t SC_BYTES = (size_t)DO * 4;
  const size_t NEED_BIG = A_BYTES + WB_BYTES + 2 * PS_BYTES + 2 * SC_BYTES;

  char* p = (char*)d_ws;
  bool bigws = (ws_size >= NEED_BIG);
  ushort* A;
  if (bigws) { A = (ushort*)p; p += A_BYTES; }
  else       { A = (ushort*)outMu; }  // park bf16 A in mu region, recompute mu last
  ushort* Wb = (ushort*)p; p += WB_BYTES;
  float* psum = (float*)p; p += PS_BYTES;
  float* psumsq = (float*)p; p += PS_BYTES;
  float* scaleA = (float*)p; p += SC_BYTES;
  float* shiftA = (float*)p;

  k_cvt<<<dim3((DO * DI) / (256 * 8)), dim3(256), 0, stream>>>(W, Wb);
  k_topk<<<dim3(NB), dim3(256), 0, stream>>>(x, center, sharp,
                                             bigws ? outMu : (float*)nullptr, A);
  k_gemm<<<dim3((NB / 256) * (DO / 256)), dim3(512), 0, stream>>>(A, Wb, bias, outY,
                                                                  psum, psumsq);
  k_bnfin<<<dim3(DO / 256), dim3(256), 0, stream>>>(psum, psumsq, gamma, beta,
                                                    scaleA, shiftA);
  k_bnapply<<<dim3((size_t)NB * DO / 4 / 256), dim3(256), 0, stream>>>(outY, scaleA,
                                                                       shiftA);
  if (!bigws) k_mu<<<dim3(NB), dim3(256), 0, stream>>>(x, center, sharp, outMu);
}

// Round 4
// 370.500 us; speedup vs baseline: 1.2380x; 1.0664x over previous
//
#include <hip/hip_runtime.h>
#include <stdint.h>

#define NB 16384       // batch rows
#define DI 2048        // d_in
#define DO 2048        // d_out
#define KTOP 256
#define LIST_CAP 384
#define MT (NB / 256)  // 256-row tiles for partial sums (64)

typedef __attribute__((ext_vector_type(4))) float f32x4;
typedef __attribute__((ext_vector_type(8))) short s16x8;
typedef __attribute__((ext_vector_type(8))) unsigned short u16x8;

// OWA weights: w(rank) = (1 - 0.9*rank/255)/140.8
#define OWA_C0 7.10227273e-3f
#define OWA_C1 2.50668449e-5f

__device__ __forceinline__ ushort f2bf(float f) {
  uint32_t u = __float_as_uint(f);
  uint32_t r = (u + 0x7FFFu + ((u >> 16) & 1u)) >> 16;  // RNE
  return (ushort)r;
}

__device__ __forceinline__ void gld_lds16(const void* g, void* l) {
  __builtin_amdgcn_global_load_lds((__attribute__((address_space(1))) void*)g,
                                   (__attribute__((address_space(3))) void*)l,
                                   16, 0, 0);
}

// ---------------------------------------------------------------------------
// K0: convert W (fp32 [DO][DI]) -> bf16
__global__ __launch_bounds__(256) void k_cvt(const float* __restrict__ W,
                                             ushort* __restrict__ Wb) {
  size_t i = ((size_t)blockIdx.x * 256 + threadIdx.x) * 8;
  float4 a = *(const float4*)(W + i);
  float4 b = *(const float4*)(W + i + 4);
  u16x8 o;
  o[0] = f2bf(a.x); o[1] = f2bf(a.y); o[2] = f2bf(a.z); o[3] = f2bf(a.w);
  o[4] = f2bf(b.x); o[5] = f2bf(b.y); o[6] = f2bf(b.z); o[7] = f2bf(b.w);
  *(u16x8*)(Wb + i) = o;
}

// ---------------------------------------------------------------------------
// K1: per-row mu + top-k(256) OWA -> A (bf16). One block (256 thr) per row.
__global__ __launch_bounds__(256) void k_topk(
    const float* __restrict__ x, const float* __restrict__ center,
    const float* __restrict__ sharp, float* __restrict__ mu_out,
    ushort* __restrict__ A) {
  __shared__ __align__(16) float w_lds[DI];   // OWA weight per column (0 if not selected)
  __shared__ uint32_t histR[8 * 256];         // 8-way replicated histogram
  __shared__ uint64_t list[LIST_CAP];         // candidate keys (bits<<32 | (DI-1-idx))
  __shared__ uint32_t scal[4];

  const int t = threadIdx.x;
  const int lane = t & 63;
  const int wv = t >> 6;
  const int row = blockIdx.x;
  const int base = t * 8;

  const float* xr = x + (size_t)row * DI + base;
  float4 xa = *(const float4*)(xr);
  float4 xb = *(const float4*)(xr + 4);
  float4 ca = *(const float4*)(center + base);
  float4 cb = *(const float4*)(center + base + 4);
  float4 sa = *(const float4*)(sharp + base);
  float4 sb = *(const float4*)(sharp + base + 4);

  float xv[8] = {xa.x, xa.y, xa.z, xa.w, xb.x, xb.y, xb.z, xb.w};
  float cv[8] = {ca.x, ca.y, ca.z, ca.w, cb.x, cb.y, cb.z, cb.w};
  float sv[8] = {sa.x, sa.y, sa.z, sa.w, sb.x, sb.y, sb.z, sb.w};
  float muv[8];
  uint32_t bits[8];
#pragma unroll
  for (int e = 0; e < 8; ++e) {
    float s = sv[e] * (xv[e] - cv[e]);
    float m = 1.0f / (1.0f + __expf(-s));
    muv[e] = m;
    bits[e] = __float_as_uint(m);  // mu>0 -> bit pattern is order-preserving
  }
  if (mu_out) {
    float4 m0; m0.x = muv[0]; m0.y = muv[1]; m0.z = muv[2]; m0.w = muv[3];
    float4 m1; m1.x = muv[4]; m1.y = muv[5]; m1.z = muv[6]; m1.w = muv[7];
    *(float4*)(mu_out + (size_t)row * DI + base) = m0;
    *(float4*)(mu_out + (size_t)row * DI + base + 4) = m1;
  }
  // zero weight array (scattered into much later; barriers in between)
  float4 z4; z4.x = z4.y = z4.z = z4.w = 0.f;
  *(float4*)(w_lds + base) = z4;
  *(float4*)(w_lds + base + 4) = z4;

  // ---- 4-pass byte radix select for the 256th-largest bit pattern ----
  uint32_t maskHi = 0, pfx = 0;
  uint32_t k_rem = KTOP;
  const uint32_t rep = (uint32_t)(t & 7) * 256u;
#pragma unroll 1
  for (int pass = 0; pass < 4; ++pass) {
    const int shift = 24 - pass * 8;
#pragma unroll
    for (int i = 0; i < 8; ++i) histR[t + 256 * i] = 0;
    __syncthreads();
#pragma unroll
    for (int e = 0; e < 8; ++e) {
      uint32_t bb = bits[e];
      if ((bb & maskHi) == pfx)
        atomicAdd(&histR[rep + ((bb >> shift) & 255u)], 1u);
    }
    __syncthreads();
    if (wv == 0) {  // single-wave suffix scan over 256 bins, no barriers
      uint32_t c0 = 0, c1 = 0, c2 = 0, c3 = 0;
#pragma unroll
      for (int r = 0; r < 8; ++r) {
        const uint32_t* h = &histR[r * 256 + lane * 4];
        c0 += h[0]; c1 += h[1]; c2 += h[2]; c3 += h[3];
      }
      uint32_t s3 = c3, s2 = c2 + s3, s1 = c1 + s2, s0 = c0 + s1;
      uint32_t Tl = s0, suf = s0;
#pragma unroll
      for (int off = 1; off < 64; off <<= 1) {
        uint32_t vsh = __shfl_down(suf, off);
        if (lane + off < 64) suf += vsh;
      }
      uint32_t above = suf - Tl;  // total of lanes > lane
      uint32_t SS[4] = {s0 + above, s1 + above, s2 + above, s3 + above};
      uint32_t cc[4] = {c0, c1, c2, c3};
#pragma unroll
      for (int j = 0; j < 4; ++j) {
        if (SS[j] >= k_rem && (SS[j] - cc[j]) < k_rem) {
          scal[0] = (uint32_t)(lane * 4 + j);
          scal[1] = SS[j] - cc[j];  // count strictly greater (this level)
        }
      }
    }
    __syncthreads();
    uint32_t v = scal[0], g = scal[1];
    pfx |= (v << shift);
    maskHi |= (0xFFu << shift);
    k_rem -= g;
  }
  const uint32_t tb = pfx;  // exact bit pattern of the 256th largest

  // ---- compact candidates (bits >= tb) ----
  if (t == 0) scal[2] = 0;
  __syncthreads();
#pragma unroll
  for (int e = 0; e < 8; ++e) {
    if (bits[e] >= tb) {
      uint32_t pos = atomicAdd(&scal[2], 1u);
      if (pos < LIST_CAP)
        list[pos] = ((uint64_t)bits[e] << 32) |
                    (uint64_t)(uint32_t)(DI - 1 - (base + e));
    }
  }
  __syncthreads();
  int L = (int)scal[2];
  if (L > LIST_CAP) L = LIST_CAP;

  // ---- exact ranks among candidates (key includes stable index tiebreak) ----
  for (int sIdx = t; sIdx < L; sIdx += 256) {
    uint64_t key = list[sIdx];
    int rank = 0;
#pragma unroll 4
    for (int j = 0; j < L; ++j) rank += (int)(list[j] > key);
    if (rank < KTOP) {
      int idx = DI - 1 - (int)((uint32_t)key & 0xFFFFFFFFu);
      w_lds[idx] = OWA_C0 - OWA_C1 * (float)rank;
    }
  }
  __syncthreads();

  // ---- emit A[b,i] = w * mu * x as bf16 (coalesced 16B stores) ----
  u16x8 ov;
#pragma unroll
  for (int e = 0; e < 8; ++e) ov[e] = f2bf(w_lds[base + e] * muv[e] * xv[e]);
  *(u16x8*)(A + (size_t)row * DI + base) = ov;
}

// ---------------------------------------------------------------------------
// K2: 256x256x64 8-phase pipelined GEMM (T2+T3+T4+T5).
// out = relu(A @ W^T + bias), fp32 out + deterministic per-tile column
// sum/sumsq partials.
//
// LDS: 4 half-slots per matrix (128x64 bf16 = 16 KB each) = ring double-buffer
// at half-tile granularity (parity (T&1)). Chunk-XOR swizzle (R2, 0-conflict):
// LDS[row][ch] = global[row][ch ^ (row&7)], read with same XOR.
//
// R4 stage schedule (maximize age at the per-tile wait):
//   (T,0): BOTH A halves of T+1 (4 loads)  [oldest slot for A]
//   (T,1): B-half0 of T+2
//   (T,2): B-half1 of T+2
//   (T,3): no stage; tail vmcnt(4) -> A(T+1) (age 3 phases) + B(T+1)
//          (issued in T-1) landed; B(T+2)'s 4 loads stay in flight.
//          End-barrier publishes before (T+1,0)'s ds_reads. T=30: vmcnt(0).
#define HALFS 8192  // ushorts per half-slot (128 rows x 64 cols)

#define STAGE_A(U, h)                                             \
  do {                                                            \
    ushort* sl = lA + (((((U) & 1) << 1) + (h)) * HALFS);         \
    gld_lds16(pA[h][0] + (size_t)(U) * 64, sl + d0);              \
    gld_lds16(pA[h][1] + (size_t)(U) * 64, sl + d1);              \
  } while (0)

#define STAGE_B(U, h)                                             \
  do {                                                            \
    ushort* sl = lB + (((((U) & 1) << 1) + (h)) * HALFS);         \
    gld_lds16(pB[h][0] + (size_t)(U) * 64, sl + d0);              \
    gld_lds16(pB[h][1] + (size_t)(U) * 64, sl + d1);              \
  } while (0)

#define MFMA_PHASE(q, A00, A01, A10, A11)                                      \
  do {                                                                         \
    __builtin_amdgcn_s_setprio(1);                                             \
    _Pragma("unroll") for (int ni = 0; ni < 4; ++ni) {                         \
      acc[2 * (q)][ni] = __builtin_amdgcn_mfma_f32_16x16x32_bf16(              \
          A00, breg[ni][0], acc[2 * (q)][ni], 0, 0, 0);                        \
      acc[2 * (q)][ni] = __builtin_amdgcn_mfma_f32_16x16x32_bf16(              \
          A01, breg[ni][1], acc[2 * (q)][ni], 0, 0, 0);                        \
      acc[2 * (q) + 1][ni] = __builtin_amdgcn_mfma_f32_16x16x32_bf16(          \
          A10, breg[ni][0], acc[2 * (q) + 1][ni], 0, 0, 0);                    \
      acc[2 * (q) + 1][ni] = __builtin_amdgcn_mfma_f32_16x16x32_bf16(          \
          A11, breg[ni][1], acc[2 * (q) + 1][ni], 0, 0, 0);                    \
    }                                                                          \
    __builtin_amdgcn_s_setprio(0);                                             \
  } while (0)

#define PHASE(q, STAGE_STMT, TAIL_STMT)                                        \
  do {                                                                         \
    s16x8 a00 = *(const s16x8*)(sAp + (32 * (q)) * 64 + aoff + c0);            \
    s16x8 a01 = *(const s16x8*)(sAp + (32 * (q)) * 64 + aoff + c1);            \
    s16x8 a10 = *(const s16x8*)(sAp + (32 * (q) + 16) * 64 + aoff + c0);       \
    s16x8 a11 = *(const s16x8*)(sAp + (32 * (q) + 16) * 64 + aoff + c1);       \
    STAGE_STMT;                                                                \
    __builtin_amdgcn_s_barrier();                                              \
    asm volatile("s_waitcnt lgkmcnt(0)" ::: "memory");                         \
    __builtin_amdgcn_sched_barrier(0);                                         \
    MFMA_PHASE(q, a00, a01, a10, a11);                                         \
    TAIL_STMT;                                                                 \
    __builtin_amdgcn_s_barrier();                                              \
  } while (0)

__global__ __launch_bounds__(512, 2) void k_gemm(
    const ushort* __restrict__ A, const ushort* __restrict__ Wb,
    const float* __restrict__ bias, float* __restrict__ outp,
    float* __restrict__ psum, float* __restrict__ psumsq) {
  __shared__ __align__(16) ushort lA[4 * HALFS];
  __shared__ __align__(16) ushort lB[4 * HALFS];

  const int t = threadIdx.x;
  const int lane = t & 63;
  const int wv = t >> 6;
  const int wm = wv >> 2;   // 0..1: which 128-row half of the M tile
  const int wn = wv & 3;    // 0..3: which 64-col strip of the N tile
  const int fr = lane & 15;
  const int kg = lane >> 4;
  const int s = fr & 7;

  // XCD-aware bijective swizzle (512 blocks, 512 % 8 == 0)
  int bid = blockIdx.x;
  int orig = (bid & 7) * 64 + (bid >> 3);
  const int nb = orig & 7;
  const int mb = orig >> 3;
  const int m0 = mb * 256;
  const int n0 = nb * 256;

  // staging address precompute: per thread, loads i=0,1 cover rows
  // i*64 + (t>>3), chunk t&7 (chunk pre-swizzled by row&7 on global src)
  const int srow0 = t >> 3;
  const int scol = ((t & 7) ^ (srow0 & 7)) * 8;
  const ushort* pA[2][2];
  const ushort* pB[2][2];
#pragma unroll
  for (int h = 0; h < 2; ++h) {
#pragma unroll
    for (int i = 0; i < 2; ++i) {
      pA[h][i] = A + (size_t)(m0 + h * 128 + i * 64 + srow0) * DI + scol;
      pB[h][i] = Wb + (size_t)(n0 + h * 128 + i * 64 + srow0) * DI + scol;
    }
  }
  const int d0 = t * 8;          // LDS dst (ushorts) for load 0
  const int d1 = (512 + t) * 8;  // load 1

  f32x4 acc[8][4];
#pragma unroll
  for (int i = 0; i < 8; ++i)
#pragma unroll
    for (int j = 0; j < 4; ++j) acc[i][j] = (f32x4){0.f, 0.f, 0.f, 0.f};

  // prologue: B(0), A(0), B(1); leave B(1) (4 loads) in flight
  STAGE_B(0, 0); STAGE_B(0, 1);
  STAGE_A(0, 0); STAGE_A(0, 1);
  STAGE_B(1, 0); STAGE_B(1, 1);
  asm volatile("s_waitcnt vmcnt(4)" ::: "memory");
  __builtin_amdgcn_s_barrier();

  // fragment read offsets (ushorts)
  const int aoff = fr * 64;
  const int c0 = (kg ^ s) * 8;
  const int c1 = ((4 + kg) ^ s) * 8;
  const int boff = ((wn & 1) * 64 + fr) * 64;

  s16x8 breg[4][2];

#pragma unroll 1
  for (int T = 0; T < 32; ++T) {
    const ushort* sAp = lA + (((T & 1) << 1) + wm) * HALFS;
    const ushort* sBp = lB + (((T & 1) << 1) + (wn >> 1)) * HALFS;

#pragma unroll
    for (int ni = 0; ni < 4; ++ni) {
      breg[ni][0] = *(const s16x8*)(sBp + ni * 1024 + boff + c0);
      breg[ni][1] = *(const s16x8*)(sBp + ni * 1024 + boff + c1);
    }
    PHASE(0, if (T < 31) { STAGE_A(T + 1, 0); STAGE_A(T + 1, 1); }, );
    PHASE(1, if (T < 30) STAGE_B(T + 2, 0), );
    PHASE(2, if (T < 30) STAGE_B(T + 2, 1), );
    PHASE(3, ,
          if (T < 30) { asm volatile("s_waitcnt vmcnt(4)" ::: "memory"); }
          else if (T == 30) { asm volatile("s_waitcnt vmcnt(0)" ::: "memory"); });
  }

  // epilogue: bias + relu + store + deterministic column partials
  __syncthreads();
  float* colsum = (float*)lA;     // reuse tile LDS
  float* colsq = colsum + 256;
  if (t < 256) { colsum[t] = 0.f; colsq[t] = 0.f; }
  __syncthreads();
#pragma unroll
  for (int ni = 0; ni < 4; ++ni) {
    const int n = n0 + wn * 64 + ni * 16 + fr;
    const float bv = bias[n];
    float cs = 0.f, cq = 0.f;
#pragma unroll
    for (int mi = 0; mi < 8; ++mi) {
      f32x4 v = acc[mi][ni];
#pragma unroll
      for (int r = 0; r < 4; ++r) {
        float zz = fmaxf(v[r] + bv, 0.f);
        outp[(size_t)(m0 + wm * 128 + mi * 16 + kg * 4 + r) * DO + n] = zz;
        cs += zz;
        cq += zz * zz;
      }
    }
    cs += __shfl_xor(cs, 16); cq += __shfl_xor(cq, 16);
    cs += __shfl_xor(cs, 32); cq += __shfl_xor(cq, 32);
    if (kg == 0) {  // exactly 2 waves (wm=0,1) add per column bin
      atomicAdd(&colsum[wn * 64 + ni * 16 + fr], cs);
      atomicAdd(&colsq[wn * 64 + ni * 16 + fr], cq);
    }
  }
  __syncthreads();
  if (t < 256) {
    psum[(size_t)mb * DO + n0 + t] = colsum[t];
    psumsq[(size_t)mb * DO + n0 + t] = colsq[t];
  }
}

// ---------------------------------------------------------------------------
// K3: finalize BN scale/shift per column
__global__ __launch_bounds__(256) void k_bnfin(
    const float* __restrict__ psum, const float* __restrict__ psumsq,
    const float* __restrict__ gamma, const float* __restrict__ beta,
    float* __restrict__ scaleA, float* __restrict__ shiftA) {
  int n = blockIdx.x * 256 + threadIdx.x;
  float s = 0.f, q = 0.f;
  for (int r = 0; r < MT; ++r) {
    s += psum[(size_t)r * DO + n];
    q += psumsq[(size_t)r * DO + n];
  }
  float mean = s * (1.0f / (float)NB);
  float var = q * (1.0f / (float)NB) - mean * mean;
  var = fmaxf(var, 0.f);
  float rstd = rsqrtf(var + 1e-5f);
  float sc = gamma[n] * rstd;
  scaleA[n] = sc;
  shiftA[n] = beta[n] - mean * sc;
}

// ---------------------------------------------------------------------------
// K4: y = out*scale + shift, in place over the y region
__global__ __launch_bounds__(256) void k_bnapply(float* __restrict__ outp,
                                                 const float* __restrict__ scaleA,
                                                 const float* __restrict__ shiftA) {
  size_t i = ((size_t)blockIdx.x * 256 + threadIdx.x) * 4;
  int n = (int)(i & (DO - 1));
  float4 v = *(float4*)(outp + i);
  float4 sc = *(const float4*)(scaleA + n);
  float4 sh = *(const float4*)(shiftA + n);
  v.x = v.x * sc.x + sh.x;
  v.y = v.y * sc.y + sh.y;
  v.z = v.z * sc.z + sh.z;
  v.w = v.w * sc.w + sh.w;
  *(float4*)(outp + i) = v;
}

// ---------------------------------------------------------------------------
// K5 (small-ws fallback): recompute mu into the mu region
__global__ __launch_bounds__(256) void k_mu(const float* __restrict__ x,
                                            const float* __restrict__ center,
                                            const float* __restrict__ sharp,
                                            float* __restrict__ mu_out) {
  const int t = threadIdx.x;
  const int row = blockIdx.x;
  const int base = t * 8;
  const float* xr = x + (size_t)row * DI + base;
  float4 xa = *(const float4*)(xr);
  float4 xb = *(const float4*)(xr + 4);
  float4 ca = *(const float4*)(center + base);
  float4 cb = *(const float4*)(center + base + 4);
  float4 sa = *(const float4*)(sharp + base);
  float4 sb = *(const float4*)(sharp + base + 4);
  float xv[8] = {xa.x, xa.y, xa.z, xa.w, xb.x, xb.y, xb.z, xb.w};
  float cv[8] = {ca.x, ca.y, ca.z, ca.w, cb.x, cb.y, cb.z, cb.w};
  float sv[8] = {sa.x, sa.y, sa.z, sa.w, sb.x, sb.y, sb.z, sb.w};
  float mu[8];
#pragma unroll
  for (int e = 0; e < 8; ++e) {
    float s = sv[e] * (xv[e] - cv[e]);
    mu[e] = 1.0f / (1.0f + __expf(-s));
  }
  float4 m0; m0.x = mu[0]; m0.y = mu[1]; m0.z = mu[2]; m0.w = mu[3];
  float4 m1; m1.x = mu[4]; m1.y = mu[5]; m1.z = mu[6]; m1.w = mu[7];
  *(float4*)(mu_out + (size_t)row * DI + base) = m0;
  *(float4*)(mu_out + (size_t)row * DI + base + 4) = m1;
}

// ---------------------------------------------------------------------------
extern "C" void kernel_launch(void* const* d_in, const int* in_sizes, int n_in,
                              void* d_out, int out_size, void* d_ws, size_t ws_size,
                              hipStream_t stream) {
  (void)in_sizes; (void)n_in; (void)out_size;
  const float* x = (const float*)d_in[0];
  const float* W = (const float*)d_in[1];
  const float* bias = (const float*)d_in[2];
  const float* center = (const float*)d_in[3];
  const float* sharp = (const float*)d_in[4];
  const float* gamma = (const float*)d_in[5];
  const float* beta = (const float*)d_in[6];
  // d_in[7] = top_k (always 256 per setup_inputs)

  float* outY = (float*)d_out;
  float* outMu = outY + (size_t)NB * DO;

  const size_t A_BYTES = (size_t)NB * DI * 2;
  const size_t WB_BYTES = (size_t)DO * DI * 2;
  const size_t PS_BYTES = (size_t)MT * DO * 4;
  const size_t SC_BYTES = (size_t)DO * 4;
  const size_t NEED_BIG = A_BYTES + WB_BYTES + 2 * PS_BYTES + 2 * SC_BYTES;

  char* p = (char*)d_ws;
  bool bigws = (ws_size >= NEED_BIG);
  ushort* A;
  if (bigws) { A = (ushort*)p; p += A_BYTES; }
  else       { A = (ushort*)outMu; }  // park bf16 A in mu region, recompute mu last
  ushort* Wb = (ushort*)p; p += WB_BYTES;
  float* psum = (float*)p; p += PS_BYTES;
  float* psumsq = (float*)p; p += PS_BYTES;
  float* scaleA = (float*)p; p += SC_BYTES;
  float* shiftA = (float*)p;

  k_cvt<<<dim3((DO * DI) / (256 * 8)), dim3(256), 0, stream>>>(W, Wb);
  k_topk<<<dim3(NB), dim3(256), 0, stream>>>(x, center, sharp,
                                             bigws ? outMu : (float*)nullptr, A);
  k_gemm<<<dim3((NB / 256) * (DO / 256)), dim3(512), 0, stream>>>(A, Wb, bias, outY,
                                                                  psum, psumsq);
  k_bnfin<<<dim3(DO / 256), dim3(256), 0, stream>>>(psum, psumsq, gamma, beta,
                                                    scaleA, shiftA);
  k_bnapply<<<dim3((size_t)NB * DO / 4 / 256), dim3(256), 0, stream>>>(outY, scaleA,
                                                                       shiftA);
  if (!bigws) k_mu<<<dim3(NB), dim3(256), 0, stream>>>(x, center, sharp, outMu);
}